// Round 7
// baseline (160.666 us; speedup 1.0000x reference)
//
#include <hip/hip_runtime.h>
#include <math.h>

#define N_ROWS 32768
#define K_CODES 8192
#define DIM 64
#define CHUNKS 4
#define CPC (K_CODES / CHUNKS)   // 2048 codes per chunk
#define TILES (CPC / 32)         // 64 tiles of 32 codes

using half8  = __attribute__((ext_vector_type(8))) _Float16;
using f32x16 = __attribute__((ext_vector_type(16))) float;

// ---------------- ws layout ----------------
#define WS_W2     0          // float w2g[8192]            32 KB
#define WS_COUNTS 32768      // int counts[8192]           32 KB
#define WS_CSUM   65536      // float csum (+pad)          16 B
#define WS_BEST   65552      // u64 best[32768]            256 KB
#define WS_X2     327696     // float x2g[32768]           128 KB
#define WS_WHL    458768     // _Float16 whl[8192][128]    2 MB (hi[64]|lo[64])

__device__ __forceinline__ void gload_lds16(const _Float16* g, _Float16* l) {
    __builtin_amdgcn_global_load_lds(
        (const __attribute__((address_space(1))) void*)g,
        (__attribute__((address_space(3))) void*)l, 16, 0, 0);
}

// ---------------- kernel 1: W split + w2 + x2 + init ----------------
// 524288 threads: g indexes W elements (8192*64) AND x float4s (32768*16).
__global__ __launch_bounds__(256) void vq_prep(const float* __restrict__ W,
                                               const float* __restrict__ x,
                                               _Float16* __restrict__ whl,
                                               float* __restrict__ w2g,
                                               float* __restrict__ x2g,
                                               unsigned long long* __restrict__ best,
                                               int* __restrict__ counts,
                                               float* __restrict__ csum) {
    int g = blockIdx.x * 256 + threadIdx.x;   // 0 .. 524287
    // --- W hi/lo split + w2 (one code per 64-lane wave) ---
    int code = g >> 6, k = g & 63;
    float w = W[g];
    _Float16 h  = (_Float16)w;
    _Float16 lo = (_Float16)(w - (float)h);
    whl[(size_t)code * 128 + k]      = h;
    whl[(size_t)code * 128 + 64 + k] = lo;
    float s = w * w;
    #pragma unroll
    for (int off = 32; off; off >>= 1) s += __shfl_down(s, off);
    if (k == 0) w2g[code] = s;
    // --- x2 (one row per 16 lanes; thread g owns x[g*4 .. g*4+3]) ---
    float4 xv = *(const float4*)(x + (size_t)g * 4);
    float ss = xv.x * xv.x + xv.y * xv.y + xv.z * xv.z + xv.w * xv.w;
    #pragma unroll
    for (int off = 8; off; off >>= 1) ss += __shfl_down(ss, off);
    if ((g & 15) == 0) x2g[g >> 4] = ss;
    // --- init ---
    if (g < N_ROWS)  best[g] = ~0ULL;
    if (g < K_CODES) counts[g] = 0;
    if (g == 0)      *csum = 0.f;
}

// ---------------- kernel 2: MFMA scores + per-row argmin ----------------
// R6-proven 2-phase loop; 2 independent MFMA chains; w2 in LDS.
__global__ __launch_bounds__(256, 4) void vq_mfma(const float* __restrict__ x,
                                                  const _Float16* __restrict__ whl,
                                                  const float* __restrict__ w2g,
                                                  unsigned long long* __restrict__ best) {
    __shared__ __align__(16) _Float16 lds[2][4096];   // 2 x 8KB
    __shared__ float w2l[CPC];                        // 8KB

    const int t     = threadIdx.x;
    const int wv    = t >> 6;
    const int l     = t & 63;
    const int ln31  = l & 31;
    const int lhalf = l >> 5;
    const int chunk = blockIdx.x & (CHUNKS - 1);
    const int rblk  = blockIdx.x / CHUNKS;
    const int rowb  = rblk * 128 + wv * 32;    // wave owns 32 rows
    const int cbase = chunk * CPC;

    // stage w2 chunk into LDS
    for (int i = t; i < CPC; i += 256) w2l[i] = w2g[cbase + i];

    // A fragments: exact f16 hi/lo split of this lane's row slice
    half8 ahi[4], alo[4];
    {
        const float* xr = x + (size_t)(rowb + ln31) * DIM + lhalf * 8;
        #pragma unroll
        for (int kt = 0; kt < 4; ++kt) {
            float4 a0 = *(const float4*)(xr + kt * 16);
            float4 a1 = *(const float4*)(xr + kt * 16 + 4);
            float fa[8] = {a0.x, a0.y, a0.z, a0.w, a1.x, a1.y, a1.z, a1.w};
            #pragma unroll
            for (int j = 0; j < 8; ++j) {
                _Float16 h = (_Float16)fa[j];
                ahi[kt][j] = h;
                alo[kt][j] = (_Float16)(fa[j] - (float)h);
            }
        }
    }

    // staging map: wave wv, instr p stages granules G = p*256 + wv*64 + lane
    const _Float16* srcp[2];
    int ldsG[2];
    #pragma unroll
    for (int p = 0; p < 2; ++p) {
        int q = p * 4 + wv;
        srcp[p] = whl + (size_t)(cbase + ln31) * 128 + ((q & 1) * 8 + lhalf + 2 * (q >> 1)) * 8;
        ldsG[p] = (p * 256 + wv * 64) * 8;   // wave-uniform base (halves)
    }

    float bv[16];
    int   bi[16];
    #pragma unroll
    for (int s2 = 0; s2 < 16; ++s2) { bv[s2] = 3.4e38f; bi[s2] = 0; }

    // prologue: stage tile 0 into buf 0
    #pragma unroll
    for (int p = 0; p < 2; ++p) gload_lds16(srcp[p], &lds[0][0] + ldsG[p]);
    __syncthreads();   // drains staging + w2l loads

    int cur = 0;
    for (int tile = 0; tile < TILES; ++tile) {
        if (tile < TILES - 1) {
            #pragma unroll
            for (int p = 0; p < 2; ++p)
                gload_lds16(srcp[p] + (tile + 1) * 4096, &lds[0][0] + (cur ^ 1) * 4096 + ldsG[p]);
        }
        const float w2v = w2l[tile * 32 + ln31];
        const _Float16* lb = &lds[0][0] + cur * 4096;

        f32x16 accA = {}, accB = {};       // 2 independent chains (len 4 / len 8)
        __builtin_amdgcn_s_setprio(1);
        #pragma unroll
        for (int kt = 0; kt < 4; ++kt) {
            half8 bh = *(const half8*)(lb + ((kt * 2 + 0) * 64 + l) * 8);
            half8 bl = *(const half8*)(lb + ((kt * 2 + 1) * 64 + l) * 8);
            accA = __builtin_amdgcn_mfma_f32_32x32x16_f16(ahi[kt], bh, accA, 0, 0, 0);
            accB = __builtin_amdgcn_mfma_f32_32x32x16_f16(alo[kt], bh, accB, 0, 0, 0);
            accB = __builtin_amdgcn_mfma_f32_32x32x16_f16(ahi[kt], bl, accB, 0, 0, 0);
        }
        __builtin_amdgcn_s_setprio(0);

        const int cc = cbase + tile * 32 + ln31;
        #pragma unroll
        for (int s2 = 0; s2 < 16; ++s2) {
            float sA = fmaf(-2.f, accA[s2], fmaf(-2.f, accB[s2], w2v));
            if (sA < bv[s2]) { bv[s2] = sA; bi[s2] = cc; }
        }
        __syncthreads();   // reads of buf `cur` done; prefetch into cur^1 drained
        cur ^= 1;
    }

    // per-row reduce across the 32 lanes sharing each row, then global merge
    #pragma unroll
    for (int s2 = 0; s2 < 16; ++s2) {
        unsigned uk = __float_as_uint(bv[s2]);
        uk = (uk >> 31) ? ~uk : (uk | 0x80000000u);   // monotone float->uint
        unsigned long long key = ((unsigned long long)uk << 32) | (unsigned)bi[s2];
        #pragma unroll
        for (int off = 16; off; off >>= 1) {
            unsigned long long o = __shfl_xor(key, off);
            key = (o < key) ? o : key;
        }
        if (ln31 == 0) {
            int rl = (s2 & 3) + 8 * (s2 >> 2) + 4 * lhalf;   // C/D row map (m74/m101)
            atomicMin(&best[rowb + rl], key);
        }
    }
}

// ---------------- kernel 3: gather z + histogram + commitment (via identity) ----------------
// dist2 = x2[row] + score, score bit-exact from the argmin key. No x re-read.
__global__ __launch_bounds__(256) void vq_gather(const float* __restrict__ W,
                                                 const unsigned long long* __restrict__ best,
                                                 const float* __restrict__ x2g,
                                                 float* __restrict__ zout,
                                                 int* __restrict__ counts,
                                                 float* __restrict__ csum) {
    int t   = threadIdx.x;
    int row = blockIdx.x * 64 + (t >> 2);
    int seg = t & 3;
    unsigned long long key = best[row];
    int idx = (int)(key & 0xFFFFFFFFULL);

    const float* wrow = W    + (size_t)idx * DIM + seg * 16;
    float*       zrow = zout + (size_t)row * DIM + seg * 16;
    #pragma unroll
    for (int j = 0; j < 16; j += 4) *(float4*)(zrow + j) = *(const float4*)(wrow + j);

    float local = 0.f;
    if (seg == 0) {
        atomicAdd(&counts[idx], 1);
        unsigned uk = (unsigned)(key >> 32);
        unsigned ob = (uk & 0x80000000u) ? (uk & 0x7FFFFFFFu) : ~uk;   // inverse monotone map
        local = x2g[row] + __uint_as_float(ob);                        // = |x-W[idx]|^2
    }
    #pragma unroll
    for (int off = 32; off; off >>= 1) local += __shfl_down(local, off);
    if ((t & 63) == 0) atomicAdd(csum, local);
}

// ---------------- kernel 4: finalize scalars ----------------
__global__ __launch_bounds__(256) void vq_final(const int* __restrict__ counts,
                                                const float* __restrict__ csum,
                                                float* __restrict__ out3) {
    __shared__ float sh[4];
    float e = 0.f;
    for (int i = threadIdx.x; i < K_CODES; i += 256) {
        float p = (float)counts[i] * (1.0f / N_ROWS);
        e += p * logf(p + 1e-10f);
    }
    #pragma unroll
    for (int off = 32; off; off >>= 1) e += __shfl_down(e, off);
    if ((threadIdx.x & 63) == 0) sh[threadIdx.x >> 6] = e;
    __syncthreads();
    if (threadIdx.x == 0) {
        float tot = sh[0] + sh[1] + sh[2] + sh[3];
        out3[0] = 0.f;
        out3[1] = csum[0] * (1.0f / ((float)N_ROWS * DIM));
        out3[2] = expf(-tot);
    }
}

extern "C" void kernel_launch(void* const* d_in, const int* in_sizes, int n_in,
                              void* d_out, int out_size, void* d_ws, size_t ws_size,
                              hipStream_t stream) {
    (void)in_sizes; (void)n_in; (void)out_size; (void)ws_size;
    const float* x = (const float*)d_in[0];
    const float* W = (const float*)d_in[1];
    float* zout = (float*)d_out;
    float* out3 = (float*)d_out + (size_t)N_ROWS * DIM;

    float*              w2g    = (float*)((char*)d_ws + WS_W2);
    int*                counts = (int*)((char*)d_ws + WS_COUNTS);
    float*              csum   = (float*)((char*)d_ws + WS_CSUM);
    unsigned long long* best   = (unsigned long long*)((char*)d_ws + WS_BEST);
    float*              x2g    = (float*)((char*)d_ws + WS_X2);
    _Float16*           whl    = (_Float16*)((char*)d_ws + WS_WHL);

    vq_prep  <<<K_CODES * DIM / 256,     256, 0, stream>>>(W, x, whl, w2g, x2g, best, counts, csum);
    vq_mfma  <<<(N_ROWS / 128) * CHUNKS, 256, 0, stream>>>(x, whl, w2g, best);
    vq_gather<<<N_ROWS / 64,             256, 0, stream>>>(W, best, x2g, zout, counts, csum);
    vq_final <<<1,                       256, 0, stream>>>(counts, csum, out3);
}